// Round 3
// baseline (880.187 us; speedup 1.0000x reference)
//
#include <hip/hip_runtime.h>

// Butterfly multiply, n=1024, log_n=10, nstacks=nblocks=1, increasing stride.
// x: (32768, 1024) f32; twiddle: (10, 512, 2, 2) f32; bias: (1024,) f32.
//
// Lane l holds elements [l*16, l*16+16) of each row.
//   stages 0..3 (stride 1..8):   within-lane register butterflies
//   stages 4..8 (stride 16..256): ds_swizzle xor (within 32-lane halves)
//   stage  9    (stride 512):     __shfl_xor(.,32) across wave halves
//
// Round-3 changes (theory: vmcnt-serialized phase bursts; HBM 31%/VALU 13%):
//  1. Twiddle stages 0..8 staged once per block into 72 KB LDS. The compute
//     phase then issues NO global loads (ds_read/ds_swizzle only, lgkmcnt),
//     so prefetched x rows stay in flight across the whole compute phase
//     (vmcnt retires in order; any vmem load inside compute would force the
//     prefetch to drain). Stage 9 twiddles stay in global/L2: their wait
//     lands ~90% through compute, after the prefetch has had time to land.
//  2. Register double-buffered x pipeline: each wave owns 8 rows = 4 groups
//     of 2; group g+1's loads are issued before group g's compute.
//  3. 72 KB LDS -> exactly 2 blocks/CU (512 thr) = 16 waves/CU, all resident
//     from t=0 (grid 512 blocks), no block churn.
//
// ws layout (produced by permute_tw_kernel), per stage s (2048 floats):
//   s<4 : lane l reads float4 ws4[s*512 + q*64 + l], q=0..7  -> t[q*4+c]
//   s>=4: lane l reads float4 ws4[s*512 + kk*64 + l], kk=0..7 giving
//         (ta[2kk], tb[2kk], ta[2kk+1], tb[2kk+1]); the i-dependent
//         mine/partner swap is folded into the permutation.

#define N 1024
#define BLOCK_THREADS 512
#define WAVES_PER_BLOCK 8
#define ROWS_PER_WAVE 8          // 4 groups x 2 rows
#define LDS_STAGES 9             // stages 0..8 in LDS (72 KB); stage 9 global

__global__ __launch_bounds__(256) void permute_tw_kernel(
    const float* __restrict__ tw, float* __restrict__ ws)
{
    const int s = blockIdx.x;          // 10 blocks, one per stage
    const int t = threadIdx.x;         // 256 threads
    #pragma unroll
    for (int it = 0; it < 8; ++it) {
        const int g = it * 256 + t;    // word index within stage, coalesced read
        const float val = tw[s * 2048 + g];
        int dst;
        if (s < 4) {
            const int l  = g >> 5;
            const int r  = g & 31;
            dst = (r >> 2) * 256 + l * 4 + (r & 3);
        } else {
            const int p  = g >> 2;         // pair index 0..511
            const int c  = g & 3;          // 2x2 entry
            const int i  = c >> 1;
            const int j  = c & 1;
            const int pl = p >> 4;
            const int k  = p & 15;
            const int lm = s - 4;
            const int m  = 1 << lm;
            const int l  = ((pl >> lm) << (lm + 1)) | (i << lm) | (pl & (m - 1));
            dst = (k >> 1) * 256 + l * 4 + (k & 1) * 2 + (j ^ i);
        }
        ws[s * 2048 + dst] = val;
    }
}

// xor-shuffle: ds_swizzle for masks <32 (BitMode pattern (m<<10)|0x1f),
// generic __shfl_xor only for the cross-half mask 32.
template<int M>
__device__ __forceinline__ float sx(float v) {
    if constexpr (M < 32) {
        return __int_as_float(__builtin_amdgcn_ds_swizzle(
            __float_as_int(v), (M << 10) | 0x1f));
    } else {
        return __shfl_xor(v, 32, 64);
    }
}

__device__ __forceinline__ void loadRow(float (&v)[16],
                                        const float* __restrict__ x,
                                        long row, int off)
{
    const float4* p = (const float4*)(x + row * N + off);
    #pragma unroll
    for (int q = 0; q < 4; ++q) {
        float4 f = p[q];
        v[q*4+0] = f.x; v[q*4+1] = f.y;
        v[q*4+2] = f.z; v[q*4+3] = f.w;
    }
}

__device__ __forceinline__ void computeStore(
    float (&v0)[16], float (&v1)[16],
    const float* ldsTw,                 // LDS, stages 0..8
    const float* __restrict__ ws,       // global, for stage 9
    const float* __restrict__ bias,
    float* __restrict__ out,
    long row, int lane, int nRows)
{
    const int off = lane * 16;

    // ---- stages 0..3: within-lane (stride 1,2,4,8), twiddles from LDS ----
    #pragma unroll
    for (int stage = 0; stage < 4; ++stage) {
        const int s = 1 << stage;
        float t[32];
        const float4* tp = (const float4*)(ldsTw + stage * 2048) + lane;
        #pragma unroll
        for (int q = 0; q < 8; ++q) {
            float4 f = tp[q * 64];
            t[q*4+0] = f.x; t[q*4+1] = f.y; t[q*4+2] = f.z; t[q*4+3] = f.w;
        }
        #pragma unroll
        for (int j = 0; j < 8; ++j) {
            const int p0 = ((j >> stage) << (stage + 1)) | (j & (s - 1));
            const int p1 = p0 | s;
            { float a = v0[p0], b = v0[p1];
              v0[p0] = t[j*4+0]*a + t[j*4+1]*b;
              v0[p1] = t[j*4+2]*a + t[j*4+3]*b; }
            { float a = v1[p0], b = v1[p1];
              v1[p0] = t[j*4+0]*a + t[j*4+1]*b;
              v1[p1] = t[j*4+2]*a + t[j*4+3]*b; }
        }
    }

    // ---- stages 4..9: cross-lane; 4..8 from LDS, 9 from global ----
#define XSTAGE(STG, BASEPTR) { \
    constexpr int M = 1 << ((STG) - 4); \
    float ta_[16], tb_[16]; \
    const float4* tp = (const float4*)((BASEPTR) + (STG) * 2048) + lane; \
    _Pragma("unroll") \
    for (int kk = 0; kk < 8; ++kk) { \
        float4 f = tp[kk * 64]; \
        ta_[2*kk+0] = f.x; tb_[2*kk+0] = f.y; \
        ta_[2*kk+1] = f.z; tb_[2*kk+1] = f.w; } \
    _Pragma("unroll") \
    for (int k = 0; k < 16; ++k) { \
        float m0 = v0[k], o0 = sx<M>(m0); \
        float m1 = v1[k], o1 = sx<M>(m1); \
        v0[k] = ta_[k]*m0 + tb_[k]*o0; \
        v1[k] = ta_[k]*m1 + tb_[k]*o1; } \
}
    XSTAGE(4, ldsTw)
    XSTAGE(5, ldsTw)
    XSTAGE(6, ldsTw)
    XSTAGE(7, ldsTw)
    XSTAGE(8, ldsTw)
    XSTAGE(9, ws)
#undef XSTAGE

    // ---- bias + store (bias reload is an L1 hit; vmcnt already drained
    //      to the stage-9 level here, so this adds no new stall) ----
    float bv[16];
    {
        const float4* bp = (const float4*)(bias + off);
        #pragma unroll
        for (int q = 0; q < 4; ++q) {
            float4 f = bp[q];
            bv[q*4+0] = f.x; bv[q*4+1] = f.y;
            bv[q*4+2] = f.z; bv[q*4+3] = f.w;
        }
    }
    if (row < nRows) {
        float4* p = (float4*)(out + row * N + off);
        #pragma unroll
        for (int q = 0; q < 4; ++q) {
            float4 f;
            f.x = v0[q*4+0] + bv[q*4+0];
            f.y = v0[q*4+1] + bv[q*4+1];
            f.z = v0[q*4+2] + bv[q*4+2];
            f.w = v0[q*4+3] + bv[q*4+3];
            p[q] = f;
        }
    }
    if (row + 1 < nRows) {
        float4* p = (float4*)(out + (row + 1) * N + off);
        #pragma unroll
        for (int q = 0; q < 4; ++q) {
            float4 f;
            f.x = v1[q*4+0] + bv[q*4+0];
            f.y = v1[q*4+1] + bv[q*4+1];
            f.z = v1[q*4+2] + bv[q*4+2];
            f.w = v1[q*4+3] + bv[q*4+3];
            p[q] = f;
        }
    }
}

__global__ __launch_bounds__(BLOCK_THREADS, 4) void butterfly_kernel(
    const float* __restrict__ x,
    const float* __restrict__ ws,
    const float* __restrict__ bias,
    float* __restrict__ out,
    int nRows)
{
    extern __shared__ float ldsTw[];   // LDS_STAGES*2048 floats = 72 KB

    // ---- stage twiddles 0..8 into LDS (coalesced, once per block) ----
    {
        const int t = threadIdx.x;
        const float4* src = (const float4*)ws;
        float4* dst = (float4*)ldsTw;
        #pragma unroll
        for (int i = 0; i < (LDS_STAGES * 2048 / 4) / BLOCK_THREADS; ++i)  // 9
            dst[i * BLOCK_THREADS + t] = src[i * BLOCK_THREADS + t];
    }
    __syncthreads();

    const int lane = threadIdx.x & 63;
    const int off = lane * 16;
    const int waveId = blockIdx.x * WAVES_PER_BLOCK + (threadIdx.x >> 6);
    const long rowBase = (long)waveId * ROWS_PER_WAVE;
    if (rowBase >= nRows) return;      // after __syncthreads: no deadlock

    float A0[16], A1[16], B0[16], B1[16];

    auto clampRow = [&](long r) { return r < nRows ? r : rowBase; };

    // prologue: group 0 -> A
    loadRow(A0, x, rowBase, off);
    loadRow(A1, x, clampRow(rowBase + 1), off);

    long r = rowBase;
    #pragma unroll 1                   // keep loop body (2 groups) in I-cache
    for (int it = 0; it < 2; ++it) {
        // prefetch next group into B, then compute current A
        loadRow(B0, x, clampRow(r + 2), off);
        loadRow(B1, x, clampRow(r + 3), off);
        computeStore(A0, A1, ldsTw, ws, bias, out, r, lane, nRows);
        if (it == 0) {                 // no prefetch past the last group
            loadRow(A0, x, clampRow(r + 4), off);
            loadRow(A1, x, clampRow(r + 5), off);
        }
        computeStore(B0, B1, ldsTw, ws, bias, out, r + 2, lane, nRows);
        r += 4;
    }
}

extern "C" void kernel_launch(void* const* d_in, const int* in_sizes, int n_in,
                              void* d_out, int out_size, void* d_ws, size_t ws_size,
                              hipStream_t stream) {
    const float* x    = (const float*)d_in[0];
    const float* tw   = (const float*)d_in[1];
    const float* bias = (const float*)d_in[2];
    float* out = (float*)d_out;
    float* ws  = (float*)d_ws;                               // needs 80 KB

    const size_t ldsBytes = (size_t)LDS_STAGES * 2048 * sizeof(float);  // 73728
    static bool attrSet = false;
    if (!attrSet) {
        hipFuncSetAttribute((const void*)butterfly_kernel,
                            hipFuncAttributeMaxDynamicSharedMemorySize,
                            (int)ldsBytes);
        attrSet = true;
    }

    // one-time (per launch) twiddle permutation into workspace
    permute_tw_kernel<<<10, 256, 0, stream>>>(tw, ws);

    const int nRows = in_sizes[0] / N;                       // 32768
    const int rowsPerBlock = WAVES_PER_BLOCK * ROWS_PER_WAVE;  // 64
    const int blocks = (nRows + rowsPerBlock - 1) / rowsPerBlock;  // 512

    butterfly_kernel<<<blocks, BLOCK_THREADS, ldsBytes, stream>>>(
        x, ws, bias, out, nRows);
}

// Round 4
// 267.320 us; speedup vs baseline: 3.2926x; 3.2926x over previous
//
#include <hip/hip_runtime.h>

// Butterfly multiply, n=1024, log_n=10, nstacks=nblocks=1, increasing stride.
// x: (32768, 1024) f32; twiddle: (10, 512, 2, 2) f32; bias: (1024,) f32.
//
// Lane l holds elements [l*16, l*16+16) of each row.
//   stages 0..3 (stride 1..8):   within-lane register butterflies
//   stages 4..8 (stride 16..256): ds_swizzle xor (within 32-lane halves)
//   stage  9    (stride 512):     __shfl_xor(.,32) across wave halves
//
// Round-4: round-3's mechanisms without its spill disaster.
//  - ALL 10 twiddle stages staged once per block into 80 KB LDS. Compute
//    phase issues ZERO vmem loads (ds_read/ds_swizzle only), so the x row
//    loads issued at wave start stay in flight / retire without any forced
//    vmcnt drain mid-compute, and per-stage twiddle latency is LDS not L1.
//  - __launch_bounds__(512) with NO min-occupancy arg. Round 3's (512,4)
//    capped VGPRs at 64 (observed) against a ~140-reg live set -> 1.3 GB
//    of scratch FETCH (10x ideal). Cap 256 lets the ~130-reg live set fit.
//  - No multi-group register pipeline: each wave owns exactly 4 rows.
//    80 KB LDS -> 2 blocks/CU, 16 waves/CU (4/SIMD) if VGPR<=128.
//
// ws layout (produced by permute_tw_kernel), per stage s (2048 floats):
//   s<4 : lane l reads float4 ws4[s*512 + q*64 + l], q=0..7  -> t[q*4+c]
//   s>=4: lane l reads float4 ws4[s*512 + kk*64 + l], kk=0..7 giving
//         (ta[2kk], tb[2kk], ta[2kk+1], tb[2kk+1]); the i-dependent
//         mine/partner swap is folded into the permutation.

#define N 1024
#define BLOCK_THREADS 512
#define WAVES_PER_BLOCK 8
#define ROWS_PER_WAVE 4
#define NSTAGES 10

__global__ __launch_bounds__(256) void permute_tw_kernel(
    const float* __restrict__ tw, float* __restrict__ ws)
{
    const int s = blockIdx.x;          // 10 blocks, one per stage
    const int t = threadIdx.x;         // 256 threads
    #pragma unroll
    for (int it = 0; it < 8; ++it) {
        const int g = it * 256 + t;    // word index within stage, coalesced read
        const float val = tw[s * 2048 + g];
        int dst;
        if (s < 4) {
            const int l  = g >> 5;
            const int r  = g & 31;
            dst = (r >> 2) * 256 + l * 4 + (r & 3);
        } else {
            const int p  = g >> 2;         // pair index 0..511
            const int c  = g & 3;          // 2x2 entry
            const int i  = c >> 1;
            const int j  = c & 1;
            const int pl = p >> 4;
            const int k  = p & 15;
            const int lm = s - 4;
            const int m  = 1 << lm;
            const int l  = ((pl >> lm) << (lm + 1)) | (i << lm) | (pl & (m - 1));
            dst = (k >> 1) * 256 + l * 4 + (k & 1) * 2 + (j ^ i);
        }
        ws[s * 2048 + dst] = val;
    }
}

// xor-shuffle: ds_swizzle for masks <32 (BitMode pattern (m<<10)|0x1f),
// generic __shfl_xor only for the cross-half mask 32.
template<int M>
__device__ __forceinline__ float sx(float v) {
    if constexpr (M < 32) {
        return __int_as_float(__builtin_amdgcn_ds_swizzle(
            __float_as_int(v), (M << 10) | 0x1f));
    } else {
        return __shfl_xor(v, 32, 64);
    }
}

__global__ __launch_bounds__(BLOCK_THREADS) void butterfly_kernel(
    const float* __restrict__ x,
    const float* __restrict__ ws,
    const float* __restrict__ bias,
    float* __restrict__ out,
    int nRows)
{
    extern __shared__ float ldsTw[];   // NSTAGES*2048 floats = 80 KB

    // ---- stage all twiddles into LDS (coalesced, once per block) ----
    {
        const int t = threadIdx.x;
        const float4* src = (const float4*)ws;
        float4* dst = (float4*)ldsTw;
        #pragma unroll
        for (int i = 0; i < (NSTAGES * 2048 / 4) / BLOCK_THREADS; ++i)  // 10
            dst[i * BLOCK_THREADS + t] = src[i * BLOCK_THREADS + t];
    }
    __syncthreads();

    const int lane = threadIdx.x & 63;
    const int off = lane * 16;
    const int waveId = blockIdx.x * WAVES_PER_BLOCK + (threadIdx.x >> 6);
    const long rowBase = (long)waveId * ROWS_PER_WAVE;
    if (rowBase >= nRows) return;      // after __syncthreads: no deadlock

    float v[ROWS_PER_WAVE][16];

    // ---- load rows (coalesced: wave covers 1024 consecutive floats) ----
    #pragma unroll
    for (int r = 0; r < ROWS_PER_WAVE; ++r) {
        const float4* p = (const float4*)(x + (rowBase + r) * N + off);
        #pragma unroll
        for (int q = 0; q < 4; ++q) {
            float4 f = p[q];
            v[r][q*4+0] = f.x; v[r][q*4+1] = f.y;
            v[r][q*4+2] = f.z; v[r][q*4+3] = f.w;
        }
    }

    // ---- stages 0..3: within-lane (stride 1,2,4,8), twiddles from LDS ----
    #pragma unroll
    for (int stage = 0; stage < 4; ++stage) {
        const int s = 1 << stage;
        float t[32];
        const float4* tp = (const float4*)(ldsTw + stage * 2048) + lane;
        #pragma unroll
        for (int q = 0; q < 8; ++q) {
            float4 f = tp[q * 64];         // ds_read_b128, conflict-free
            t[q*4+0] = f.x; t[q*4+1] = f.y; t[q*4+2] = f.z; t[q*4+3] = f.w;
        }
        #pragma unroll
        for (int r = 0; r < ROWS_PER_WAVE; ++r) {
            #pragma unroll
            for (int j = 0; j < 8; ++j) {
                const int p0 = ((j >> stage) << (stage + 1)) | (j & (s - 1));
                const int p1 = p0 | s;
                float a = v[r][p0], b = v[r][p1];
                v[r][p0] = t[j*4+0] * a + t[j*4+1] * b;
                v[r][p1] = t[j*4+2] * a + t[j*4+3] * b;
            }
        }
    }

    // ---- stages 4..9: cross-lane, twiddles from LDS ----
#define XSTAGE(STG) { \
    constexpr int M = 1 << ((STG) - 4); \
    float ta_[16], tb_[16]; \
    const float4* tp = (const float4*)(ldsTw + (STG) * 2048) + lane; \
    _Pragma("unroll") \
    for (int kk = 0; kk < 8; ++kk) { \
        float4 f = tp[kk * 64]; \
        ta_[2*kk+0] = f.x; tb_[2*kk+0] = f.y; \
        ta_[2*kk+1] = f.z; tb_[2*kk+1] = f.w; } \
    _Pragma("unroll") \
    for (int r = 0; r < ROWS_PER_WAVE; ++r) { \
        _Pragma("unroll") \
        for (int k = 0; k < 16; ++k) { \
            float mine  = v[r][k]; \
            float other = sx<M>(mine); \
            v[r][k] = ta_[k] * mine + tb_[k] * other; } } \
}
    XSTAGE(4)
    XSTAGE(5)
    XSTAGE(6)
    XSTAGE(7)
    XSTAGE(8)
    XSTAGE(9)
#undef XSTAGE

    // ---- bias + store ----
    float bv[16];
    {
        const float4* bp = (const float4*)(bias + off);
        #pragma unroll
        for (int q = 0; q < 4; ++q) {
            float4 f = bp[q];
            bv[q*4+0] = f.x; bv[q*4+1] = f.y;
            bv[q*4+2] = f.z; bv[q*4+3] = f.w;
        }
    }
    #pragma unroll
    for (int r = 0; r < ROWS_PER_WAVE; ++r) {
        float4* p = (float4*)(out + (rowBase + r) * N + off);
        #pragma unroll
        for (int q = 0; q < 4; ++q) {
            float4 f;
            f.x = v[r][q*4+0] + bv[q*4+0];
            f.y = v[r][q*4+1] + bv[q*4+1];
            f.z = v[r][q*4+2] + bv[q*4+2];
            f.w = v[r][q*4+3] + bv[q*4+3];
            p[q] = f;
        }
    }
}

extern "C" void kernel_launch(void* const* d_in, const int* in_sizes, int n_in,
                              void* d_out, int out_size, void* d_ws, size_t ws_size,
                              hipStream_t stream) {
    const float* x    = (const float*)d_in[0];
    const float* tw   = (const float*)d_in[1];
    const float* bias = (const float*)d_in[2];
    float* out = (float*)d_out;
    float* ws  = (float*)d_ws;                               // needs 80 KB

    const size_t ldsBytes = (size_t)NSTAGES * 2048 * sizeof(float);  // 81920
    static bool attrSet = false;
    if (!attrSet) {
        hipFuncSetAttribute((const void*)butterfly_kernel,
                            hipFuncAttributeMaxDynamicSharedMemorySize,
                            (int)ldsBytes);
        attrSet = true;
    }

    // one-time (per launch) twiddle permutation into workspace
    permute_tw_kernel<<<10, 256, 0, stream>>>(tw, ws);

    const int nRows = in_sizes[0] / N;                       // 32768
    const int rowsPerBlock = WAVES_PER_BLOCK * ROWS_PER_WAVE;  // 32
    const int blocks = (nRows + rowsPerBlock - 1) / rowsPerBlock;  // 1024

    butterfly_kernel<<<blocks, BLOCK_THREADS, ldsBytes, stream>>>(
        x, ws, bias, out, nRows);
}

// Round 5
// 255.109 us; speedup vs baseline: 3.4502x; 1.0479x over previous
//
#include <hip/hip_runtime.h>

// Butterfly multiply, n=1024, log_n=10, nstacks=nblocks=1, increasing stride.
// x: (32768, 1024) f32; twiddle: (10, 512, 2, 2) f32; bias: (1024,) f32.
//
// Round-5: kill the DS pipe bottleneck (was 464 DS insts/wave: 384 swizzle
// + 80 twiddle reads; DS pipe is per-CU shared, ~45 us of pure throughput
// plus serial swizzle->FMA chains).
//   stages 0..3 (bits 0-3, in-reg q):    register butterflies, tw from LDS
//   stages 4,5  (bits 4,5 = lane 0,1):   DPP quad_perm (VALU, not DS!)
//   TRANSPOSE   (LDS, per row):          ownership (lane=e[9:4],reg=e[3:0])
//                                        -> (lane=e[5:0], reg=e[9:6])
//   stages 6..9 (bits 6-9, in-reg j):    register butterflies, tw DIRECT
//                                        from global (coalesced b128!)
// DS per wave: 32 tw reads + 16 writes + 64 reads (transpose) ~= 116 (was 464).
//
// Twiddle indexing, stages 6-9 (derivation): after transpose, element
// e = lane + 64*j. Stage s pairs regs (j0, j0|2^(s-6)); twiddle pair index
// = e with bit s deleted = lane + 64*t (t = butterfly counter 0..7). So
// lane l reads float4 tw[s*2048 + 4*(l+64t)] -> lane-stride 16B, perfectly
// coalesced, full 2x2 per lane (lane owns both pair elements). No permute.
//
// Transpose buffer (per wave, 1280 floats): addr(e) = (e>>4)*20 + (e&15).
// Write: lane l holds e=16l+q -> float4 at (l*20+4k), lanes spread over all
// 32 banks (20l mod 32 cycles 8 distinct 4-bank windows) = structural-min.
// Read: e = l+64j -> addr = 80j + 20*(l>>4) + (l&15), <=3-way conflict.
//
// ws (permuted twiddle) layout, per stage s (2048 floats):
//   s<4 : lane l reads float4 ws4[s*512 + q*64 + l], q=0..7  -> t[q*4+c]
//   s in {4,5}: lane l reads float4 ws4[s*512 + kk*64 + l], kk=0..7 giving
//         (ta[2kk], tb[2kk], ta[2kk+1], tb[2kk+1]); i-dependent mine/partner
//         swap folded into the permutation.

#define N 1024
#define BLOCK_THREADS 512
#define WAVES_PER_BLOCK 8
#define ROWS_PER_WAVE 4
#define TBUF_FLOATS 1280           // 64 * 20
#define LDS_TW_FLOATS 8192         // stages 0..3 permuted
#define LDS_TOTAL_FLOATS (LDS_TW_FLOATS + WAVES_PER_BLOCK * TBUF_FLOATS) // 18432

__global__ __launch_bounds__(256) void permute_tw_kernel(
    const float* __restrict__ tw, float* __restrict__ ws)
{
    const int s = blockIdx.x;          // 10 blocks, one per stage
    const int t = threadIdx.x;         // 256 threads
    #pragma unroll
    for (int it = 0; it < 8; ++it) {
        const int g = it * 256 + t;    // word index within stage, coalesced read
        const float val = tw[s * 2048 + g];
        int dst;
        if (s < 4) {
            const int l  = g >> 5;
            const int r  = g & 31;
            dst = (r >> 2) * 256 + l * 4 + (r & 3);
        } else {
            const int p  = g >> 2;         // pair index 0..511
            const int c  = g & 3;          // 2x2 entry
            const int i  = c >> 1;
            const int j  = c & 1;
            const int pl = p >> 4;
            const int k  = p & 15;
            const int lm = s - 4;
            const int m  = 1 << lm;
            const int l  = ((pl >> lm) << (lm + 1)) | (i << lm) | (pl & (m - 1));
            dst = (k >> 1) * 256 + l * 4 + (k & 1) * 2 + (j ^ i);
        }
        ws[s * 2048 + dst] = val;
    }
}

// quad_perm DPP xor-exchange within 4-lane quads (VALU pipe, not DS).
// xor1: perm [1,0,3,2] -> ctrl 0xB1 ; xor2: perm [2,3,0,1] -> ctrl 0x4E
template<int CTRL>
__device__ __forceinline__ float qperm(float v) {
    return __int_as_float(__builtin_amdgcn_mov_dpp(
        __float_as_int(v), CTRL, 0xF, 0xF, true));
}

__global__ __launch_bounds__(BLOCK_THREADS) void butterfly_kernel(
    const float* __restrict__ x,
    const float* __restrict__ tw,      // original twiddle (stages 6..9 direct)
    const float* __restrict__ ws,      // permuted twiddle (stages 0..5)
    const float* __restrict__ bias,
    float* __restrict__ out,
    int nRows)
{
    extern __shared__ float lds[];     // [0,8192): tw stages 0..3; then tbufs

    // ---- stage twiddles 0..3 into LDS (coalesced, once per block) ----
    {
        const int t = threadIdx.x;
        const float4* src = (const float4*)ws;      // first 2048 float4 = s0..3
        float4* dst = (float4*)lds;
        #pragma unroll
        for (int i = 0; i < (LDS_TW_FLOATS / 4) / BLOCK_THREADS; ++i)  // 4
            dst[i * BLOCK_THREADS + t] = src[i * BLOCK_THREADS + t];
    }
    __syncthreads();

    const int lane = threadIdx.x & 63;
    const int wib  = threadIdx.x >> 6;
    float* tbuf = lds + LDS_TW_FLOATS + wib * TBUF_FLOATS;

    const int waveId = blockIdx.x * WAVES_PER_BLOCK + wib;
    const long rowBase = (long)waveId * ROWS_PER_WAVE;
    if (rowBase >= nRows) return;      // after __syncthreads: no deadlock

    const int off = lane * 16;
    float v[ROWS_PER_WAVE][16];

    // ---- load rows (coalesced: wave covers 1024 consecutive floats) ----
    #pragma unroll
    for (int r = 0; r < ROWS_PER_WAVE; ++r) {
        const float4* p = (const float4*)(x + (rowBase + r) * N + off);
        #pragma unroll
        for (int q = 0; q < 4; ++q) {
            float4 f = p[q];
            v[r][q*4+0] = f.x; v[r][q*4+1] = f.y;
            v[r][q*4+2] = f.z; v[r][q*4+3] = f.w;
        }
    }

    // ---- stages 0..3: within-lane (bits 0-3), twiddles from LDS ----
    #pragma unroll
    for (int stage = 0; stage < 4; ++stage) {
        const int s = 1 << stage;
        float t[32];
        const float4* tp = (const float4*)(lds + stage * 2048) + lane;
        #pragma unroll
        for (int q = 0; q < 8; ++q) {
            float4 f = tp[q * 64];         // ds_read_b128, conflict-free
            t[q*4+0] = f.x; t[q*4+1] = f.y; t[q*4+2] = f.z; t[q*4+3] = f.w;
        }
        #pragma unroll
        for (int r = 0; r < ROWS_PER_WAVE; ++r) {
            #pragma unroll
            for (int j = 0; j < 8; ++j) {
                const int p0 = ((j >> stage) << (stage + 1)) | (j & (s - 1));
                const int p1 = p0 | s;
                float a = v[r][p0], b = v[r][p1];
                v[r][p0] = t[j*4+0] * a + t[j*4+1] * b;
                v[r][p1] = t[j*4+2] * a + t[j*4+3] * b;
            }
        }
    }

    // ---- stages 4,5: lane-xor 1,2 via DPP quad_perm; ta/tb from ws ----
#define DSTAGE(STG, CTRL) { \
    float ta_[16], tb_[16]; \
    const float4* tp = (const float4*)(ws + (STG) * 2048) + lane; \
    _Pragma("unroll") \
    for (int kk = 0; kk < 8; ++kk) { \
        float4 f = tp[kk * 64];            /* coalesced global, L1/L2 hit */ \
        ta_[2*kk+0] = f.x; tb_[2*kk+0] = f.y; \
        ta_[2*kk+1] = f.z; tb_[2*kk+1] = f.w; } \
    _Pragma("unroll") \
    for (int r = 0; r < ROWS_PER_WAVE; ++r) { \
        _Pragma("unroll") \
        for (int k = 0; k < 16; ++k) { \
            float mine  = v[r][k]; \
            float other = qperm<CTRL>(mine); \
            v[r][k] = ta_[k] * mine + tb_[k] * other; } } \
}
    DSTAGE(4, 0xB1)   // xor lane^1
    DSTAGE(5, 0x4E)   // xor lane^2
#undef DSTAGE

    // ---- transpose ownership: (lane=e[9:4], reg=e[3:0]) -> (lane=e[5:0],
    //      reg=e[9:6]); per row through the per-wave padded LDS buffer ----
    {
        float4* tb4 = (float4*)tbuf;                  // write addr: l*20+4k
        const int rbase = (lane >> 4) * 20 + (lane & 15);
        #pragma unroll
        for (int r = 0; r < ROWS_PER_WAVE; ++r) {
            #pragma unroll
            for (int k = 0; k < 4; ++k) {
                float4 f;
                f.x = v[r][4*k+0]; f.y = v[r][4*k+1];
                f.z = v[r][4*k+2]; f.w = v[r][4*k+3];
                tb4[lane * 5 + k] = f;                // 80B-aligned, 16B ok
            }
            // compiler inserts the lgkmcnt waits (plain HIP LDS aliasing)
            #pragma unroll
            for (int j = 0; j < 16; ++j)
                v[r][j] = tbuf[rbase + j * 80];       // e = lane + 64j
        }
    }

    // ---- stages 6..9: within-lane (bits 6-9 = reg bits 0-3),
    //      twiddles DIRECT from tw, coalesced b128 (no permutation) ----
    #pragma unroll
    for (int m = 0; m < 4; ++m) {
        const int s = 1 << m;
        float t[32];
        const float4* tp = (const float4*)(tw + (6 + m) * 2048) + lane;
        #pragma unroll
        for (int q = 0; q < 8; ++q) {
            float4 f = tp[q * 64];         // lane-stride 16B: coalesced
            t[q*4+0] = f.x; t[q*4+1] = f.y; t[q*4+2] = f.z; t[q*4+3] = f.w;
        }
        #pragma unroll
        for (int r = 0; r < ROWS_PER_WAVE; ++r) {
            #pragma unroll
            for (int j = 0; j < 8; ++j) {
                const int p0 = ((j >> m) << (m + 1)) | (j & (s - 1));
                const int p1 = p0 | s;
                float a = v[r][p0], b = v[r][p1];
                v[r][p0] = t[j*4+0] * a + t[j*4+1] * b;
                v[r][p1] = t[j*4+2] * a + t[j*4+3] * b;
            }
        }
    }

    // ---- bias + store (transposed ownership: element = lane + 64j) ----
    float bv[16];
    {
        const float* bp = bias + lane;
        #pragma unroll
        for (int j = 0; j < 16; ++j)
            bv[j] = bp[j * 64];            // coalesced b32, L1 hit
    }
    #pragma unroll
    for (int r = 0; r < ROWS_PER_WAVE; ++r) {
        float* op = out + (rowBase + r) * N + lane;
        #pragma unroll
        for (int j = 0; j < 16; ++j)
            op[j * 64] = v[r][j] + bv[j];  // coalesced 256B stores
    }
}

extern "C" void kernel_launch(void* const* d_in, const int* in_sizes, int n_in,
                              void* d_out, int out_size, void* d_ws, size_t ws_size,
                              hipStream_t stream) {
    const float* x    = (const float*)d_in[0];
    const float* tw   = (const float*)d_in[1];
    const float* bias = (const float*)d_in[2];
    float* out = (float*)d_out;
    float* ws  = (float*)d_ws;                               // needs 80 KB

    const size_t ldsBytes = (size_t)LDS_TOTAL_FLOATS * sizeof(float); // 73728
    static bool attrSet = false;
    if (!attrSet) {
        hipFuncSetAttribute((const void*)butterfly_kernel,
                            hipFuncAttributeMaxDynamicSharedMemorySize,
                            (int)ldsBytes);
        attrSet = true;
    }

    // one-time (per launch) twiddle permutation into workspace
    permute_tw_kernel<<<10, 256, 0, stream>>>(tw, ws);

    const int nRows = in_sizes[0] / N;                       // 32768
    const int rowsPerBlock = WAVES_PER_BLOCK * ROWS_PER_WAVE;  // 32
    const int blocks = (nRows + rowsPerBlock - 1) / rowsPerBlock;  // 1024

    butterfly_kernel<<<blocks, BLOCK_THREADS, ldsBytes, stream>>>(
        x, tw, ws, bias, out, nRows);
}